// Round 1
// baseline (293.762 us; speedup 1.0000x reference)
//
#include <hip/hip_runtime.h>
#include <hip/hip_bf16.h>
#include <stdint.h>

// SelfAttentionBlock: B=4, C=256, H=W=64 (N=4096), CQK=32.
// Kernel 1 (proj): q/k/v 1x1-conv projections in fp32 VALU, outputs f16 to ws.
//   ws layout: Qt[b][n][32] (f16), Kt[b][n][32] (f16), V[b][c][n] (f16)  ~10.5MB
// Kernel 2 (attn): flash attention, mfma_f32_16x16x32_f16.
//   Per block: (b, 64-row i-strip). 4 waves: QK^T/softmax split by i (16 rows/wave),
//   PV split by c (64 channels/wave). K/V staged to LDS via global_load_lds(16)
//   with XOR granule swizzle pre-applied on the *global* source address (m173),
//   P through swizzled LDS. Online softmax (m,l per row), scale broadcast via LDS.

#define NB 4
#define CD 256
#define ND 4096
#define CQ 32

typedef __attribute__((ext_vector_type(4))) float f32x4;
typedef __attribute__((ext_vector_type(8))) _Float16 f16x8;
typedef __attribute__((ext_vector_type(4))) unsigned short u16x4;

__device__ __forceinline__ unsigned short f2h(float f) {
    _Float16 h = (_Float16)f;
    union { _Float16 h; unsigned short u; } cv; cv.h = h;
    return cv.u;
}

__device__ __forceinline__ void gl_lds16(const void* g, void* l) {
    __builtin_amdgcn_global_load_lds(
        (const __attribute__((address_space(1))) unsigned int*)g,
        (__attribute__((address_space(3))) unsigned int*)l, 16, 0, 0);
}

// ---------------- projection kernel ----------------
// grid: NB*64 blocks (one per (b, 64-col tile)), 512 threads (8 waves).
// Each wave owns 40 output rows (rows 0..31 = q, 32..63 = k, 64..319 = v),
// each lane owns one of the 64 columns. x tile staged in LDS (64KB fp32).
__global__ __launch_bounds__(512) void proj_kernel(
    const float* __restrict__ x,
    const float* __restrict__ wq, const float* __restrict__ bq,
    const float* __restrict__ wk, const float* __restrict__ bk,
    const float* __restrict__ wv, const float* __restrict__ bv,
    unsigned short* __restrict__ Qt, unsigned short* __restrict__ Kt,
    unsigned short* __restrict__ V)
{
    __shared__ float xs[CD][64];
    const int b  = blockIdx.x >> 6;
    const int n0 = (blockIdx.x & 63) << 6;
    const int tid = threadIdx.x;

    {   // load x[b, :, n0:n0+64] -> LDS, float4-coalesced
        const float* xb = x + (size_t)b * CD * ND + n0;
        for (int idx = tid; idx < CD * 16; idx += 512) {
            const int c = idx >> 4, ch = idx & 15;
            *reinterpret_cast<f32x4*>(&xs[c][ch * 4]) =
                *reinterpret_cast<const f32x4*>(xb + (size_t)c * ND + ch * 4);
        }
    }
    __syncthreads();

    const int lane = tid & 63;
    const int g = __builtin_amdgcn_readfirstlane(tid >> 6);  // wave id, uniform
    const int n = n0 + lane;

    for (int q4 = 0; q4 < 10; ++q4) {
        const int o0 = g * 40 + q4 * 4;  // quad of output rows; never straddles segments
        const float* wr[4];
        float bs[4];
        int kind;
        if (o0 < 32) {
            kind = 0;
#pragma unroll
            for (int j = 0; j < 4; ++j) { wr[j] = wq + (o0 + j) * CD; bs[j] = bq[o0 + j]; }
        } else if (o0 < 64) {
            kind = 1;
#pragma unroll
            for (int j = 0; j < 4; ++j) { wr[j] = wk + (o0 - 32 + j) * CD; bs[j] = bk[o0 - 32 + j]; }
        } else {
            kind = 2;
#pragma unroll
            for (int j = 0; j < 4; ++j) { wr[j] = wv + (o0 - 64 + j) * CD; bs[j] = bv[o0 - 64 + j]; }
        }
        float acc[4] = {0.f, 0.f, 0.f, 0.f};
        for (int c = 0; c < CD; c += 8) {
            float xv[8];
#pragma unroll
            for (int u = 0; u < 8; ++u) xv[u] = xs[c + u][lane];
#pragma unroll
            for (int j = 0; j < 4; ++j) {
#pragma unroll
                for (int u = 0; u < 8; ++u) acc[j] = fmaf(wr[j][c + u], xv[u], acc[j]);
            }
        }
        u16x4 h;
#pragma unroll
        for (int j = 0; j < 4; ++j) h[j] = f2h(fmaxf(acc[j] + bs[j], 0.f));

        if (kind == 0) {
            *reinterpret_cast<u16x4*>(Qt + ((size_t)(b * ND + n)) * CQ + o0) = h;
        } else if (kind == 1) {
            *reinterpret_cast<u16x4*>(Kt + ((size_t)(b * ND + n)) * CQ + (o0 - 32)) = h;
        } else {
#pragma unroll
            for (int j = 0; j < 4; ++j)
                V[((size_t)(b * CD + (o0 - 64 + j))) * ND + n] = h[j];
        }
    }
}

// ---------------- flash attention kernel ----------------
// grid: NB*64 blocks (one per (b, 64-row i-strip)), 256 threads (4 waves).
__global__ __launch_bounds__(256) void attn_kernel(
    const unsigned short* __restrict__ Qt, const unsigned short* __restrict__ Kt,
    const unsigned short* __restrict__ V, const float* __restrict__ x,
    const float* __restrict__ gamma, float* __restrict__ out)
{
    // K tile: [j=64][c=32] f16, 64B rows, granule swizzle ^((j&3)<<4)
    __shared__ __align__(16) unsigned char k_lds[64 * 64];
    // V tile: [c=256][j=64] f16, 128B rows, granule swizzle ^((c&7)<<4)
    __shared__ __align__(16) unsigned char v_lds[256 * 128];
    // P tile: [i=64][j=64] f16, 128B rows, granule swizzle ^((i&7)<<4)
    __shared__ __align__(16) unsigned char p_lds[64 * 128];
    __shared__ float scale_lds[64];
    __shared__ float l_lds[64];

    const int tid  = threadIdx.x;
    const int lane = tid & 63;
    const int w    = __builtin_amdgcn_readfirstlane(tid >> 6);  // wave 0..3
    const int m16  = lane & 15;
    const int g4   = lane >> 4;
    const int b    = blockIdx.x >> 6;
    const int i0   = (blockIdx.x & 63) << 6;

    // Hoisted Q A-fragment for this wave's 16 rows (A: row=lane%16, k=(lane/16)*8+u)
    const f16x8 qfrag = *reinterpret_cast<const f16x8*>(
        Qt + ((size_t)(b * ND + i0 + w * 16 + m16)) * CQ + g4 * 8);

    f32x4 oacc[4][4];  // [i_subtile][c_subtile]; wave's c-slice = [w*64, w*64+64)
#pragma unroll
    for (int a = 0; a < 4; ++a)
#pragma unroll
        for (int c = 0; c < 4; ++c) oacc[a][c] = (f32x4){0.f, 0.f, 0.f, 0.f};
    float mrow[4] = {-1e30f, -1e30f, -1e30f, -1e30f};
    float lrow[4] = {0.f, 0.f, 0.f, 0.f};
    const f32x4 zero4 = {0.f, 0.f, 0.f, 0.f};

    for (int step = 0; step < ND / 64; ++step) {
        const int j0 = step * 64;
        __syncthreads();  // previous step's LDS reads done

        // stage K rows [w*16, w*16+16): 1 instr, lane -> row l/4, granule l%4
        {
            const int j  = w * 16 + (lane >> 2);
            const int gl = (lane & 3) ^ (j & 3);
            gl_lds16(Kt + ((size_t)(b * ND + j0 + j)) * CQ + gl * 8,
                     &k_lds[w * 16 * 64]);
        }
        // stage V channel rows [w*64, w*64+64): 8 instrs, lane -> row l/8, granule l%8
#pragma unroll
        for (int kk = 0; kk < 8; ++kk) {
            const int c  = w * 64 + kk * 8 + (lane >> 3);
            const int gl = (lane & 7) ^ (c & 7);
            gl_lds16(V + ((size_t)(b * CD + c)) * ND + j0 + gl * 8,
                     &v_lds[(w * 64 + kk * 8) * 128]);
        }
        __syncthreads();  // compiler drains vmcnt(0) before barrier

        // QK^T: S[16 rows of wave w][64 j], 4 MFMAs (K=32 in one shot)
        f32x4 s[4];
#pragma unroll
        for (int t = 0; t < 4; ++t) {
            const int j  = t * 16 + m16;
            const int ka = (j * 64 + g4 * 16) ^ ((j & 3) << 4);
            const f16x8 kf = *reinterpret_cast<const f16x8*>(&k_lds[ka]);
            s[t] = __builtin_amdgcn_mfma_f32_16x16x32_f16(qfrag, kf, zero4, 0, 0, 0);
        }
        // online softmax over this wave's 16 rows (C/D: row=(l>>4)*4+r, col=l&15)
        float sc[4];
#pragma unroll
        for (int r = 0; r < 4; ++r) {
            float v = fmaxf(fmaxf(s[0][r], s[1][r]), fmaxf(s[2][r], s[3][r]));
            v = fmaxf(v, __shfl_xor(v, 1, 16));
            v = fmaxf(v, __shfl_xor(v, 2, 16));
            v = fmaxf(v, __shfl_xor(v, 4, 16));
            v = fmaxf(v, __shfl_xor(v, 8, 16));
            const float mnew = fmaxf(mrow[r], v);
            sc[r]   = __expf(mrow[r] - mnew);
            mrow[r] = mnew;
        }
#pragma unroll
        for (int t = 0; t < 4; ++t)
#pragma unroll
            for (int r = 0; r < 4; ++r) s[t][r] = __expf(s[t][r] - mrow[r]);
#pragma unroll
        for (int r = 0; r < 4; ++r) {
            float rs = (s[0][r] + s[1][r]) + (s[2][r] + s[3][r]);
            rs += __shfl_xor(rs, 1, 16);
            rs += __shfl_xor(rs, 2, 16);
            rs += __shfl_xor(rs, 4, 16);
            rs += __shfl_xor(rs, 8, 16);
            lrow[r] = lrow[r] * sc[r] + rs;
        }
        // P -> LDS (f16, swizzled)
#pragma unroll
        for (int t = 0; t < 4; ++t)
#pragma unroll
            for (int r = 0; r < 4; ++r) {
                const int i  = w * 16 + g4 * 4 + r;
                const int j  = t * 16 + m16;
                const int pa = (i * 128 + j * 2) ^ ((i & 7) << 4);
                *reinterpret_cast<unsigned short*>(&p_lds[pa]) = f2h(s[t][r]);
            }
        if (m16 == 0) {
#pragma unroll
            for (int r = 0; r < 4; ++r) scale_lds[w * 16 + g4 * 4 + r] = sc[r];
        }
        __syncthreads();  // P + scales visible to all waves

        // rescale O by per-row scale
#pragma unroll
        for (int is = 0; is < 4; ++is) {
#pragma unroll
            for (int r = 0; r < 4; ++r) {
                const float scv = scale_lds[is * 16 + g4 * 4 + r];
#pragma unroll
                for (int cs = 0; cs < 4; ++cs) oacc[is][cs][r] *= scv;
            }
        }
        // PV: O[i][c] += P[i][j] * V[c][j]; B-frags reused across i-subtiles
#pragma unroll
        for (int jh = 0; jh < 2; ++jh) {
            f16x8 vfr[4];
#pragma unroll
            for (int cs = 0; cs < 4; ++cs) {
                const int c  = w * 64 + cs * 16 + m16;
                const int va = (c * 128 + jh * 64 + g4 * 16) ^ ((c & 7) << 4);
                vfr[cs] = *reinterpret_cast<const f16x8*>(&v_lds[va]);
            }
#pragma unroll
            for (int is = 0; is < 4; ++is) {
                const int i  = is * 16 + m16;
                const int pa = (i * 128 + jh * 64 + g4 * 16) ^ ((i & 7) << 4);
                const f16x8 pf = *reinterpret_cast<const f16x8*>(&p_lds[pa]);
#pragma unroll
                for (int cs = 0; cs < 4; ++cs)
                    oacc[is][cs] = __builtin_amdgcn_mfma_f32_16x16x32_f16(
                        pf, vfr[cs], oacc[is][cs], 0, 0, 0);
            }
        }
    }

    if (m16 == 0) {
#pragma unroll
        for (int r = 0; r < 4; ++r) l_lds[w * 16 + g4 * 4 + r] = lrow[r];
    }
    __syncthreads();

    const float gm = gamma[0];
#pragma unroll
    for (int is = 0; is < 4; ++is) {
#pragma unroll
        for (int r = 0; r < 4; ++r) {
            const float linv = 1.0f / l_lds[is * 16 + g4 * 4 + r];
            const int i = i0 + is * 16 + g4 * 4 + r;
#pragma unroll
            for (int cs = 0; cs < 4; ++cs) {
                const int c = w * 64 + cs * 16 + m16;
                const size_t idx = ((size_t)(b * CD + c)) * ND + i;
                out[idx] = gm * (oacc[is][cs][r] * linv) + x[idx];
            }
        }
    }
}

extern "C" void kernel_launch(void* const* d_in, const int* in_sizes, int n_in,
                              void* d_out, int out_size, void* d_ws, size_t ws_size,
                              hipStream_t stream) {
    const float* x     = (const float*)d_in[0];
    const float* wq    = (const float*)d_in[1];
    const float* bq    = (const float*)d_in[2];
    const float* wk    = (const float*)d_in[3];
    const float* bk    = (const float*)d_in[4];
    const float* wv    = (const float*)d_in[5];
    const float* bv    = (const float*)d_in[6];
    const float* gamma = (const float*)d_in[7];

    unsigned short* Qt = (unsigned short*)d_ws;              // 4*4096*32 f16 = 1MB
    unsigned short* Kt = Qt + (size_t)NB * ND * CQ;          // 1MB
    unsigned short* V  = Kt + (size_t)NB * ND * CQ;          // 4*256*4096 f16 = 8MB
    float* out = (float*)d_out;

    proj_kernel<<<dim3(NB * 64), dim3(512), 0, stream>>>(x, wq, bq, wk, bk, wv, bv, Qt, Kt, V);
    attn_kernel<<<dim3(NB * 64), dim3(256), 0, stream>>>(Qt, Kt, V, x, gamma, out);
}

// Round 2
// 171.187 us; speedup vs baseline: 1.7160x; 1.7160x over previous
//
#include <hip/hip_runtime.h>
#include <hip/hip_bf16.h>
#include <stdint.h>

// SelfAttentionBlock: B=4, C=256, H=W=64 (N=4096), CQK=32.
// Pipeline:
//   wcvt: W(320x256) fp32 -> f16  (Wh)
//   xcvt: x (B,C,N) fp32 -> f16 transposed xh[b][n][c]  (LDS transpose)
//   proj: register MFMA GEMM, A=Wh rows, B=xh rows -> Qt[n][32], Kt[n][32], V[c][n] (f16)
//   attn: flash attention, mfma 16x16x32 f16, double-buffered K/V staging via
//         global_load_lds(16) w/ pre-swizzled source; raw lgkm-only barrier mid-step
//         so prefetch vmcnt survives until end-of-step __syncthreads.

#define NB 4
#define CD 256
#define ND 4096
#define CQ 32

typedef __attribute__((ext_vector_type(4))) float f32x4;
typedef __attribute__((ext_vector_type(8))) _Float16 f16x8;
typedef __attribute__((ext_vector_type(4))) unsigned short u16x4;
typedef __attribute__((ext_vector_type(8))) unsigned short u16x8;

static __device__ __forceinline__ unsigned short f2h(float f) {
    union { _Float16 h; unsigned short u; } cv; cv.h = (_Float16)f; return cv.u;
}

__device__ __forceinline__ void gl_lds16(const void* g, void* l) {
    __builtin_amdgcn_global_load_lds(
        (const __attribute__((address_space(1))) unsigned int*)g,
        (__attribute__((address_space(3))) unsigned int*)l, 16, 0, 0);
}

// ---------------- W fp32 -> f16 (rows 0..31 q, 32..63 k, 64..319 v) ----------------
__global__ __launch_bounds__(256) void wcvt_kernel(
    const float* __restrict__ wq, const float* __restrict__ wk,
    const float* __restrict__ wv, unsigned short* __restrict__ Wh)
{
    const int idx = blockIdx.x * 256 + threadIdx.x;   // 80 blocks -> 20480 f32x4 exactly
    const int m = idx >> 6, kq = (idx & 63) << 2;
    const float* src = (m < 32) ? (wq + (size_t)m * CD + kq)
                     : (m < 64) ? (wk + (size_t)(m - 32) * CD + kq)
                                : (wv + (size_t)(m - 64) * CD + kq);
    const f32x4 v = *reinterpret_cast<const f32x4*>(src);
    u16x4 h;
#pragma unroll
    for (int u = 0; u < 4; ++u) h[u] = f2h(v[u]);
    *reinterpret_cast<u16x4*>(Wh + (size_t)m * CD + kq) = h;
}

// ---------------- x fp32 (b,c,n) -> xh f16 [b][n][c] ----------------
// grid: b(4) x ctile(4) x ntile(64) = 1024 blocks, 256 threads. 64x64 LDS transpose.
__global__ __launch_bounds__(256) void xcvt_kernel(
    const float* __restrict__ x, unsigned short* __restrict__ xh)
{
    __shared__ unsigned short xt[64 * 72];   // padded rows: 72 elems = 144B
    const int t  = threadIdx.x;
    const int nt = blockIdx.x & 63, ct = (blockIdx.x >> 6) & 3, b = blockIdx.x >> 8;
    const int n0 = nt << 6, c0 = ct << 6;

    const float* xb = x + ((size_t)(b * CD + c0)) * ND + n0;
#pragma unroll
    for (int s = t; s < 1024; s += 256) {
        const int c = s >> 4, nq = (s & 15) << 2;
        const f32x4 v = *reinterpret_cast<const f32x4*>(xb + (size_t)c * ND + nq);
        u16x4 h;
#pragma unroll
        for (int u = 0; u < 4; ++u) h[u] = f2h(v[u]);
        *reinterpret_cast<u16x4*>(&xt[c * 72 + nq]) = h;
    }
    __syncthreads();

    const int n = t >> 2, cb = (t & 3) << 4;
    u16x8 o0, o1;
#pragma unroll
    for (int u = 0; u < 8; ++u) o0[u] = xt[(cb + u) * 72 + n];
#pragma unroll
    for (int u = 0; u < 8; ++u) o1[u] = xt[(cb + 8 + u) * 72 + n];
    unsigned short* dst = xh + ((size_t)(b * ND + n0 + n)) * CD + c0 + cb;
    *reinterpret_cast<u16x8*>(dst)     = o0;
    *reinterpret_cast<u16x8*>(dst + 8) = o1;
}

// ---------------- projection: register MFMA GEMM ----------------
// grid: NB*64 blocks (b, 64-col n-tile), 320 threads = 5 waves.
// wave w owns output rows [w*64, w*64+64) of M=320 (=[wq;wk;wv]), all 64 n-cols.
__global__ __launch_bounds__(320) void proj_kernel(
    const unsigned short* __restrict__ Wh, const unsigned short* __restrict__ xh,
    const float* __restrict__ bq, const float* __restrict__ bk,
    const float* __restrict__ bv,
    unsigned short* __restrict__ Qt, unsigned short* __restrict__ Kt,
    unsigned short* __restrict__ V)
{
    const int tid = threadIdx.x;
    const int lane = tid & 63;
    const int w = __builtin_amdgcn_readfirstlane(tid >> 6);  // 0..4
    const int m16 = lane & 15, g4 = lane >> 4;
    const int b = blockIdx.x >> 6, n0 = (blockIdx.x & 63) << 6;

    f32x4 acc[4][4];
#pragma unroll
    for (int a = 0; a < 4; ++a)
#pragma unroll
        for (int c = 0; c < 4; ++c) acc[a][c] = (f32x4){0.f, 0.f, 0.f, 0.f};

    const unsigned short* Wrow = Wh + (size_t)(w * 64 + m16) * CD;
    const unsigned short* Xrow = xh + ((size_t)(b * ND + n0 + m16)) * CD;

#pragma unroll
    for (int ks = 0; ks < 8; ++ks) {
        const int ko = ks * 32 + g4 * 8;
        f16x8 af[4], bf[4];
#pragma unroll
        for (int ms = 0; ms < 4; ++ms)
            af[ms] = *reinterpret_cast<const f16x8*>(Wrow + (size_t)ms * 16 * CD + ko);
#pragma unroll
        for (int ns = 0; ns < 4; ++ns)
            bf[ns] = *reinterpret_cast<const f16x8*>(Xrow + (size_t)ns * 16 * CD + ko);
#pragma unroll
        for (int ms = 0; ms < 4; ++ms)
#pragma unroll
            for (int ns = 0; ns < 4; ++ns)
                acc[ms][ns] = __builtin_amdgcn_mfma_f32_16x16x32_f16(
                    af[ms], bf[ns], acc[ms][ns], 0, 0, 0);
    }

    // epilogue: bias + relu + f16 store
#pragma unroll
    for (int ms = 0; ms < 4; ++ms) {
        const int seg = w * 64 + ms * 16;   // wave-uniform segment base
        const int mb  = seg + g4 * 4;       // +r for r=0..3
        f32x4 bias;
        if (seg < 32)       bias = *reinterpret_cast<const f32x4*>(bq + mb);
        else if (seg < 64)  bias = *reinterpret_cast<const f32x4*>(bk + mb - 32);
        else                bias = *reinterpret_cast<const f32x4*>(bv + mb - 64);
#pragma unroll
        for (int ns = 0; ns < 4; ++ns) {
            const int n = n0 + ns * 16 + m16;
            u16x4 h;
#pragma unroll
            for (int r = 0; r < 4; ++r) h[r] = f2h(fmaxf(acc[ms][ns][r] + bias[r], 0.f));
            if (seg < 32) {
                *reinterpret_cast<u16x4*>(Qt + ((size_t)(b * ND + n)) * CQ + mb) = h;
            } else if (seg < 64) {
                *reinterpret_cast<u16x4*>(Kt + ((size_t)(b * ND + n)) * CQ + (mb - 32)) = h;
            } else {
#pragma unroll
                for (int r = 0; r < 4; ++r)
                    V[((size_t)(b * CD + (mb - 64 + r))) * ND + n] = h[r];
            }
        }
    }
}

// ---------------- flash attention, double-buffered staging ----------------
// grid: NB*64 blocks (b, 64-row i-strip), 256 threads (4 waves).
__global__ __launch_bounds__(256) void attn_kernel(
    const unsigned short* __restrict__ Qt, const unsigned short* __restrict__ Kt,
    const unsigned short* __restrict__ V, const float* __restrict__ x,
    const float* __restrict__ gamma, float* __restrict__ out)
{
    // K tile: [j=64][c=32] f16, 64B rows, granule swizzle ^((j&3)<<4)
    __shared__ __align__(16) unsigned char k_lds[2][64 * 64];
    // V tile: [c=256][j=64] f16, 128B rows, granule swizzle ^((c&7)<<4)
    __shared__ __align__(16) unsigned char v_lds[2][256 * 128];
    // P tile: [i=64][j=64] f16, 128B rows, granule swizzle ^((i&7)<<4)
    __shared__ __align__(16) unsigned char p_lds[64 * 128];
    __shared__ float scale_lds[64];
    __shared__ float l_lds[64];

    const int tid  = threadIdx.x;
    const int lane = tid & 63;
    const int w    = __builtin_amdgcn_readfirstlane(tid >> 6);  // wave 0..3
    const int m16  = lane & 15;
    const int g4   = lane >> 4;
    // XCD-aware swizzle: 256 blocks, 8 XCDs -> contiguous 32-block chunks per XCD
    const int wg   = (blockIdx.x & 7) * 32 + (blockIdx.x >> 3);
    const int b    = wg >> 6;
    const int i0   = (wg & 63) << 6;

    // Hoisted Q A-fragment (A: row=lane%16, k=(lane/16)*8+u)
    const f16x8 qfrag = *reinterpret_cast<const f16x8*>(
        Qt + ((size_t)(b * ND + i0 + w * 16 + m16)) * CQ + g4 * 8);

    // pre-swizzled staging source pointers (m173 pattern: linear LDS dest, swizzled global src)
    const int kj  = w * 16 + (lane >> 2);
    const int kgl = (lane & 3) ^ (kj & 3);
    const unsigned short* kp = Kt + ((size_t)(b * ND + kj)) * CQ + kgl * 8;
    const unsigned short* vp[8];
#pragma unroll
    for (int kk = 0; kk < 8; ++kk) {
        const int c  = w * 64 + kk * 8 + (lane >> 3);
        const int gl = (lane & 7) ^ (c & 7);
        vp[kk] = V + ((size_t)(b * CD + c)) * ND + gl * 8;
    }

    f32x4 oacc[4][4];  // [i_subtile][c_subtile]; wave's c-slice = [w*64, w*64+64)
#pragma unroll
    for (int a = 0; a < 4; ++a)
#pragma unroll
        for (int c = 0; c < 4; ++c) oacc[a][c] = (f32x4){0.f, 0.f, 0.f, 0.f};
    float mrow[4] = {-1e30f, -1e30f, -1e30f, -1e30f};
    float lrow[4] = {0.f, 0.f, 0.f, 0.f};
    const f32x4 zero4 = {0.f, 0.f, 0.f, 0.f};

    auto STAGE = [&](int bb, int j0) {
        gl_lds16(kp + (size_t)j0 * CQ, &k_lds[bb][w * 16 * 64]);
#pragma unroll
        for (int kk = 0; kk < 8; ++kk)
            gl_lds16(vp[kk] + j0, &v_lds[bb][(w * 64 + kk * 8) * 128]);
    };

    STAGE(0, 0);
    __syncthreads();   // drains vmcnt(0): buffer 0 ready
    int cur = 0;

    for (int step = 0; step < ND / 64; ++step) {
        if (step < ND / 64 - 1) STAGE(cur ^ 1, (step + 1) << 6);  // prefetch in flight across compute

        // QK^T: S[16 rows of wave w][64 j], 4 MFMAs (K=32 in one shot)
        f32x4 s[4];
        __builtin_amdgcn_s_setprio(1);
#pragma unroll
        for (int t = 0; t < 4; ++t) {
            const int j  = t * 16 + m16;
            const int ka = ((j * 64 + g4 * 16) ^ ((j & 3) << 4));
            const f16x8 kf = *reinterpret_cast<const f16x8*>(&k_lds[cur][ka]);
            s[t] = __builtin_amdgcn_mfma_f32_16x16x32_f16(qfrag, kf, zero4, 0, 0, 0);
        }
        __builtin_amdgcn_s_setprio(0);

        // online softmax over this wave's 16 rows (C/D: row=(l>>4)*4+r, col=l&15)
        float sc[4];
#pragma unroll
        for (int r = 0; r < 4; ++r) {
            float v = fmaxf(fmaxf(s[0][r], s[1][r]), fmaxf(s[2][r], s[3][r]));
            v = fmaxf(v, __shfl_xor(v, 1, 16));
            v = fmaxf(v, __shfl_xor(v, 2, 16));
            v = fmaxf(v, __shfl_xor(v, 4, 16));
            v = fmaxf(v, __shfl_xor(v, 8, 16));
            const float mnew = fmaxf(mrow[r], v);
            sc[r]   = __expf(mrow[r] - mnew);
            mrow[r] = mnew;
        }
#pragma unroll
        for (int t = 0; t < 4; ++t)
#pragma unroll
            for (int r = 0; r < 4; ++r) s[t][r] = __expf(s[t][r] - mrow[r]);
#pragma unroll
        for (int r = 0; r < 4; ++r) {
            float rs = (s[0][r] + s[1][r]) + (s[2][r] + s[3][r]);
            rs += __shfl_xor(rs, 1, 16);
            rs += __shfl_xor(rs, 2, 16);
            rs += __shfl_xor(rs, 4, 16);
            rs += __shfl_xor(rs, 8, 16);
            lrow[r] = lrow[r] * sc[r] + rs;
        }
        // P -> LDS (f16, swizzled)
#pragma unroll
        for (int t = 0; t < 4; ++t)
#pragma unroll
            for (int r = 0; r < 4; ++r) {
                const int i  = w * 16 + g4 * 4 + r;
                const int j  = t * 16 + m16;
                const int pa = (i * 128 + j * 2) ^ ((i & 7) << 4);
                *reinterpret_cast<unsigned short*>(&p_lds[pa]) = f2h(s[t][r]);
            }
        if (m16 == 0) {
#pragma unroll
            for (int r = 0; r < 4; ++r) scale_lds[w * 16 + g4 * 4 + r] = sc[r];
        }
        // P + scales visible to all waves; lgkm-only barrier keeps prefetch vmcnt in flight
        asm volatile("s_waitcnt lgkmcnt(0)\n\ts_barrier" ::: "memory");

        // rescale O by per-row scale
#pragma unroll
        for (int is = 0; is < 4; ++is) {
#pragma unroll
            for (int r = 0; r < 4; ++r) {
                const float scv = scale_lds[is * 16 + g4 * 4 + r];
#pragma unroll
                for (int cs = 0; cs < 4; ++cs) oacc[is][cs][r] *= scv;
            }
        }
        // PV: O[i][c] += P[i][j] * V[c][j]; B-frags reused across i-subtiles
        __builtin_amdgcn_s_setprio(1);
#pragma unroll
        for (int jh = 0; jh < 2; ++jh) {
            f16x8 vfr[4];
#pragma unroll
            for (int cs = 0; cs < 4; ++cs) {
                const int c  = w * 64 + cs * 16 + m16;
                const int va = ((c * 128 + jh * 64 + g4 * 16) ^ ((c & 7) << 4));
                vfr[cs] = *reinterpret_cast<const f16x8*>(&v_lds[cur][va]);
            }
#pragma unroll
            for (int is = 0; is < 4; ++is) {
                const int i  = is * 16 + m16;
                const int pa = ((i * 128 + jh * 64 + g4 * 16) ^ ((i & 7) << 4));
                const f16x8 pf = *reinterpret_cast<const f16x8*>(&p_lds[pa]);
#pragma unroll
                for (int cs = 0; cs < 4; ++cs)
                    oacc[is][cs] = __builtin_amdgcn_mfma_f32_16x16x32_f16(
                        pf, vfr[cs], oacc[is][cs], 0, 0, 0);
            }
        }
        __builtin_amdgcn_s_setprio(0);

        __syncthreads();   // drains vmcnt(0): prefetched buffer ready; LDS reads done
        cur ^= 1;
    }

    if (m16 == 0) {
#pragma unroll
        for (int r = 0; r < 4; ++r) l_lds[w * 16 + g4 * 4 + r] = lrow[r];
    }
    __syncthreads();

    const float gm = gamma[0];
#pragma unroll
    for (int is = 0; is < 4; ++is) {
#pragma unroll
        for (int r = 0; r < 4; ++r) {
            const float linv = 1.0f / l_lds[is * 16 + g4 * 4 + r];
            const int i = i0 + is * 16 + g4 * 4 + r;
#pragma unroll
            for (int cs = 0; cs < 4; ++cs) {
                const int c = w * 64 + cs * 16 + m16;
                const size_t idx = ((size_t)(b * CD + c)) * ND + i;
                out[idx] = gm * (oacc[is][cs][r] * linv) + x[idx];
            }
        }
    }
}

extern "C" void kernel_launch(void* const* d_in, const int* in_sizes, int n_in,
                              void* d_out, int out_size, void* d_ws, size_t ws_size,
                              hipStream_t stream) {
    const float* x     = (const float*)d_in[0];
    const float* wq    = (const float*)d_in[1];
    const float* bq    = (const float*)d_in[2];
    const float* wk    = (const float*)d_in[3];
    const float* bk    = (const float*)d_in[4];
    const float* wv    = (const float*)d_in[5];
    const float* bv    = (const float*)d_in[6];
    const float* gamma = (const float*)d_in[7];

    unsigned short* Qt = (unsigned short*)d_ws;               // 4*4096*32  f16 = 1MB
    unsigned short* Kt = Qt + (size_t)NB * ND * CQ;           // 1MB
    unsigned short* V  = Kt + (size_t)NB * ND * CQ;           // 4*256*4096 f16 = 8MB
    unsigned short* Wh = V + (size_t)NB * CD * ND;            // 320*256    f16 = 160KB
    unsigned short* xh = Wh + (size_t)320 * CD;               // 4*4096*256 f16 = 8MB
    float* out = (float*)d_out;

    wcvt_kernel<<<dim3(80),      dim3(256), 0, stream>>>(wq, wk, wv, Wh);
    xcvt_kernel<<<dim3(1024),    dim3(256), 0, stream>>>(x, xh);
    proj_kernel<<<dim3(NB * 64), dim3(320), 0, stream>>>(Wh, xh, bq, bk, bv, Qt, Kt, V);
    attn_kernel<<<dim3(NB * 64), dim3(256), 0, stream>>>(Qt, Kt, V, x, gamma, out);
}

// Round 3
// 103.853 us; speedup vs baseline: 2.8286x; 1.6484x over previous
//
#include <hip/hip_runtime.h>
#include <hip/hip_bf16.h>
#include <stdint.h>

// SelfAttentionBlock: B=4, C=256, H=W=64 (N=4096), CQK=32.
//   wcvt: W fp32 -> f16;  xcvt: x -> f16 transposed xh[b][n][c]
//   proj: register MFMA GEMM -> Qt[n][32]*log2e, Kt[n][32], V[c][n] (f16)
//   attn: flash attention, 8 waves = 2 j-split groups (flash-decoding merge),
//         DPP reductions, log2-domain softmax, defer-max, reg-staged K.

#define NB 4
#define CD 256
#define ND 4096
#define CQ 32
#define LOG2E 1.4426950408889634f

typedef __attribute__((ext_vector_type(4))) float f32x4;
typedef __attribute__((ext_vector_type(8))) _Float16 f16x8;
typedef __attribute__((ext_vector_type(4))) unsigned short u16x4;
typedef __attribute__((ext_vector_type(8))) unsigned short u16x8;
typedef __attribute__((ext_vector_type(4))) unsigned int u32x4;

static __device__ __forceinline__ unsigned short f2h(float f) {
    union { _Float16 h; unsigned short u; } cv; cv.h = (_Float16)f; return cv.u;
}
static __device__ __forceinline__ float fexp2(float xv) {
    float r; asm("v_exp_f32 %0, %1" : "=v"(r) : "v"(xv)); return r;
}
// reductions across the 16-lane row via DPP (VALU pipe, no LDS)
static __device__ __forceinline__ float dmax16(float v) {
    int t;
    t = __builtin_amdgcn_update_dpp(0, __float_as_int(v), 0xB1, 0xF, 0xF, true);   // quad_perm xor1
    v = fmaxf(v, __int_as_float(t));
    t = __builtin_amdgcn_update_dpp(0, __float_as_int(v), 0x4E, 0xF, 0xF, true);   // quad_perm xor2
    v = fmaxf(v, __int_as_float(t));
    t = __builtin_amdgcn_update_dpp(0, __float_as_int(v), 0x124, 0xF, 0xF, true);  // row_ror:4
    v = fmaxf(v, __int_as_float(t));
    t = __builtin_amdgcn_update_dpp(0, __float_as_int(v), 0x128, 0xF, 0xF, true);  // row_ror:8
    v = fmaxf(v, __int_as_float(t));
    return v;
}
static __device__ __forceinline__ float dsum16(float v) {
    int t;
    t = __builtin_amdgcn_update_dpp(0, __float_as_int(v), 0xB1, 0xF, 0xF, true);
    v += __int_as_float(t);
    t = __builtin_amdgcn_update_dpp(0, __float_as_int(v), 0x4E, 0xF, 0xF, true);
    v += __int_as_float(t);
    t = __builtin_amdgcn_update_dpp(0, __float_as_int(v), 0x124, 0xF, 0xF, true);
    v += __int_as_float(t);
    t = __builtin_amdgcn_update_dpp(0, __float_as_int(v), 0x128, 0xF, 0xF, true);
    v += __int_as_float(t);
    return v;
}
__device__ __forceinline__ void gl_lds16(const void* gp, void* l) {
    __builtin_amdgcn_global_load_lds(
        (const __attribute__((address_space(1))) unsigned int*)gp,
        (__attribute__((address_space(3))) unsigned int*)l, 16, 0, 0);
}

// ---------------- W fp32 -> f16 ----------------
__global__ __launch_bounds__(256) void wcvt_kernel(
    const float* __restrict__ wq, const float* __restrict__ wk,
    const float* __restrict__ wv, unsigned short* __restrict__ Wh)
{
    const int idx = blockIdx.x * 256 + threadIdx.x;
    const int m = idx >> 6, kq = (idx & 63) << 2;
    const float* src = (m < 32) ? (wq + (size_t)m * CD + kq)
                     : (m < 64) ? (wk + (size_t)(m - 32) * CD + kq)
                                : (wv + (size_t)(m - 64) * CD + kq);
    const f32x4 v = *reinterpret_cast<const f32x4*>(src);
    u16x4 h;
#pragma unroll
    for (int u = 0; u < 4; ++u) h[u] = f2h(v[u]);
    *reinterpret_cast<u16x4*>(Wh + (size_t)m * CD + kq) = h;
}

// ---------------- x fp32 (b,c,n) -> xh f16 [b][n][c] ----------------
__global__ __launch_bounds__(256) void xcvt_kernel(
    const float* __restrict__ x, unsigned short* __restrict__ xh)
{
    __shared__ unsigned short xt[64 * 72];
    const int t  = threadIdx.x;
    const int nt = blockIdx.x & 63, ct = (blockIdx.x >> 6) & 3, b = blockIdx.x >> 8;
    const int n0 = nt << 6, c0 = ct << 6;

    const float* xb = x + ((size_t)(b * CD + c0)) * ND + n0;
#pragma unroll
    for (int s = t; s < 1024; s += 256) {
        const int c = s >> 4, nq = (s & 15) << 2;
        const f32x4 v = *reinterpret_cast<const f32x4*>(xb + (size_t)c * ND + nq);
        u16x4 h;
#pragma unroll
        for (int u = 0; u < 4; ++u) h[u] = f2h(v[u]);
        *reinterpret_cast<u16x4*>(&xt[c * 72 + nq]) = h;
    }
    __syncthreads();

    const int n = t >> 2, cb = (t & 3) << 4;
    u16x8 o0, o1;
#pragma unroll
    for (int u = 0; u < 8; ++u) o0[u] = xt[(cb + u) * 72 + n];
#pragma unroll
    for (int u = 0; u < 8; ++u) o1[u] = xt[(cb + 8 + u) * 72 + n];
    unsigned short* dst = xh + ((size_t)(b * ND + n0 + n)) * CD + c0 + cb;
    *reinterpret_cast<u16x8*>(dst)     = o0;
    *reinterpret_cast<u16x8*>(dst + 8) = o1;
}

// ---------------- projection: register MFMA GEMM ----------------
__global__ __launch_bounds__(320) void proj_kernel(
    const unsigned short* __restrict__ Wh, const unsigned short* __restrict__ xh,
    const float* __restrict__ bq, const float* __restrict__ bk,
    const float* __restrict__ bv,
    unsigned short* __restrict__ Qt, unsigned short* __restrict__ Kt,
    unsigned short* __restrict__ V)
{
    const int tid = threadIdx.x;
    const int lane = tid & 63;
    const int w = __builtin_amdgcn_readfirstlane(tid >> 6);
    const int m16 = lane & 15, g4 = lane >> 4;
    const int b = blockIdx.x >> 6, n0 = (blockIdx.x & 63) << 6;

    f32x4 acc[4][4];
#pragma unroll
    for (int a = 0; a < 4; ++a)
#pragma unroll
        for (int c = 0; c < 4; ++c) acc[a][c] = (f32x4){0.f, 0.f, 0.f, 0.f};

    const unsigned short* Wrow = Wh + (size_t)(w * 64 + m16) * CD;
    const unsigned short* Xrow = xh + ((size_t)(b * ND + n0 + m16)) * CD;

#pragma unroll
    for (int ks = 0; ks < 8; ++ks) {
        const int ko = ks * 32 + g4 * 8;
        f16x8 af[4], bf[4];
#pragma unroll
        for (int ms = 0; ms < 4; ++ms)
            af[ms] = *reinterpret_cast<const f16x8*>(Wrow + (size_t)ms * 16 * CD + ko);
#pragma unroll
        for (int ns = 0; ns < 4; ++ns)
            bf[ns] = *reinterpret_cast<const f16x8*>(Xrow + (size_t)ns * 16 * CD + ko);
#pragma unroll
        for (int ms = 0; ms < 4; ++ms)
#pragma unroll
            for (int ns = 0; ns < 4; ++ns)
                acc[ms][ns] = __builtin_amdgcn_mfma_f32_16x16x32_f16(
                    af[ms], bf[ns], acc[ms][ns], 0, 0, 0);
    }

#pragma unroll
    for (int ms = 0; ms < 4; ++ms) {
        const int seg = w * 64 + ms * 16;
        const int mb  = seg + g4 * 4;
        f32x4 bias;
        if (seg < 32)       bias = *reinterpret_cast<const f32x4*>(bq + mb);
        else if (seg < 64)  bias = *reinterpret_cast<const f32x4*>(bk + mb - 32);
        else                bias = *reinterpret_cast<const f32x4*>(bv + mb - 64);
#pragma unroll
        for (int ns = 0; ns < 4; ++ns) {
            const int n = n0 + ns * 16 + m16;
            u16x4 h;
            if (seg < 32) {
#pragma unroll
                for (int r = 0; r < 4; ++r)
                    h[r] = f2h(fmaxf(acc[ms][ns][r] + bias[r], 0.f) * LOG2E);
                *reinterpret_cast<u16x4*>(Qt + ((size_t)(b * ND + n)) * CQ + mb) = h;
            } else if (seg < 64) {
#pragma unroll
                for (int r = 0; r < 4; ++r) h[r] = f2h(fmaxf(acc[ms][ns][r] + bias[r], 0.f));
                *reinterpret_cast<u16x4*>(Kt + ((size_t)(b * ND + n)) * CQ + (mb - 32)) = h;
            } else {
#pragma unroll
                for (int r = 0; r < 4; ++r)
                    V[((size_t)(b * CD + (mb - 64 + r))) * ND + n] =
                        f2h(fmaxf(acc[ms][ns][r] + bias[r], 0.f));
            }
        }
    }
}

// ---------------- flash attention: 8 waves, 2 j-split groups ----------------
// grid: NB*64 blocks (b, 64-row i-strip), 512 threads.
// Group g (waves g*4..g*4+3) processes j-chunks step*128 + g*64 .. +64 with its
// own online-softmax state; epilogue merges the two groups (exact).
__global__ __launch_bounds__(512, 2) void attn_kernel(
    const unsigned short* __restrict__ Qt, const unsigned short* __restrict__ Kt,
    const unsigned short* __restrict__ V, const float* __restrict__ x,
    const float* __restrict__ gamma, float* __restrict__ out)
{
    __shared__ __align__(16) unsigned char v_lds[2][2][256 * 128]; // [group][buf]
    __shared__ __align__(16) unsigned char k_lds[2][64 * 64];      // [group]
    __shared__ __align__(16) unsigned char p_lds[2][64 * 128];     // [group]
    __shared__ float scale_lds[2][64];
    __shared__ float mfin[2][64];
    __shared__ float lfin[2][64];
    __shared__ int   flags[2][2];   // [group][step parity]

    const int tid  = threadIdx.x;
    const int lane = tid & 63;
    const int w8   = __builtin_amdgcn_readfirstlane(tid >> 6);
    const int g    = w8 >> 2;       // j-group
    const int ws   = w8 & 3;        // strip / c-slice within group
    const int m16  = lane & 15;
    const int g4   = lane >> 4;
    const int wg   = (blockIdx.x & 7) * 32 + (blockIdx.x >> 3);  // XCD swizzle
    const int b    = wg >> 6;
    const int i0   = (wg & 63) << 6;

    if (tid < 4) flags[tid >> 1][tid & 1] = 0;

    const f16x8 qfrag = *reinterpret_cast<const f16x8*>(
        Qt + ((size_t)(b * ND + i0 + ws * 16 + m16)) * CQ + g4 * 8);

    // V staging: wave stages channels ws*64..+64 of its group's j-half.
    // (c&7) == (lane>>3)&7 for all kk, so one pre-swizzled base works for all kk.
    const int vgl = (lane & 7) ^ ((lane >> 3) & 7);
    const unsigned short* vpb =
        V + ((size_t)(b * CD + ws * 64 + (lane >> 3))) * ND + vgl * 8;
    // K reg-staging: lane loads local row kj, granule lane&3 (linear source)
    const int kj = ws * 16 + (lane >> 2);
    const unsigned short* kp = Kt + ((size_t)(b * ND + kj)) * CQ + (lane & 3) * 8;
    const int kwaddr = (kj * 64 + (lane & 3) * 16) ^ ((kj & 3) << 4);

    f32x4 oacc[4][4];
#pragma unroll
    for (int a = 0; a < 4; ++a)
#pragma unroll
        for (int c = 0; c < 4; ++c) oacc[a][c] = (f32x4){0.f, 0.f, 0.f, 0.f};
    float mrow[4] = {-1e30f, -1e30f, -1e30f, -1e30f};
    float lrow[4] = {0.f, 0.f, 0.f, 0.f};
    const f32x4 zero4 = {0.f, 0.f, 0.f, 0.f};

    auto STAGEV = [&](int bb, int jg) {
#pragma unroll
        for (int kk = 0; kk < 8; ++kk)
            gl_lds16(vpb + (size_t)kk * 8 * ND + jg,
                     &v_lds[g][bb][(ws * 64 + kk * 8) * 128]);
    };

    {   // prologue: stage step-0 tiles
        const int jg0 = g * 64;
        const u32x4 k0 = *reinterpret_cast<const u32x4*>(kp + (size_t)jg0 * CQ);
        STAGEV(0, jg0);
        *reinterpret_cast<u32x4*>(&k_lds[g][kwaddr]) = k0;  // waits vmcnt for k0 only
    }
    __syncthreads();
    int cur = 0;

    for (int step = 0; step < 32; ++step) {
        u32x4 kn;
        const bool havenext = step < 31;
        if (havenext) {
            const int jgn = (step + 1) * 128 + g * 64;
            kn = *reinterpret_cast<const u32x4*>(kp + (size_t)jgn * CQ);
            STAGEV(cur ^ 1, jgn);   // stays in flight across the whole step
        }

        // ---- QK^T (K local 64 j of this group's half) ----
        f32x4 s[4];
        __builtin_amdgcn_s_setprio(1);
#pragma unroll
        for (int t = 0; t < 4; ++t) {
            const int jj = t * 16 + m16;
            const int ka = (jj * 64 + g4 * 16) ^ ((jj & 3) << 4);
            const f16x8 kf = *reinterpret_cast<const f16x8*>(&k_lds[g][ka]);
            s[t] = __builtin_amdgcn_mfma_f32_16x16x32_f16(qfrag, kf, zero4, 0, 0, 0);
        }
        __builtin_amdgcn_s_setprio(0);

        // ---- online softmax (log2 domain), defer-max ----
        float pmax[4];
#pragma unroll
        for (int r = 0; r < 4; ++r)
            pmax[r] = dmax16(fmaxf(fmaxf(s[0][r], s[1][r]), fmaxf(s[2][r], s[3][r])));
        bool near = true;
#pragma unroll
        for (int r = 0; r < 4; ++r) near = near && (pmax[r] <= mrow[r] + 8.0f);
        const bool dorescale = (__ballot(near) != ~0ull);
        float sc[4];
        if (dorescale) {
#pragma unroll
            for (int r = 0; r < 4; ++r) {
                const float mnew = fmaxf(mrow[r], pmax[r]);
                sc[r] = fexp2(mrow[r] - mnew);
                mrow[r] = mnew;
            }
            if (lane == 0) flags[g][step & 1] = 1;
        } else {
#pragma unroll
            for (int r = 0; r < 4; ++r) sc[r] = 1.0f;
        }
#pragma unroll
        for (int t = 0; t < 4; ++t)
#pragma unroll
            for (int r = 0; r < 4; ++r) s[t][r] = fexp2(s[t][r] - mrow[r]);
#pragma unroll
        for (int r = 0; r < 4; ++r) {
            const float rs = dsum16(((s[0][r] + s[1][r]) + (s[2][r] + s[3][r])));
            lrow[r] = lrow[r] * sc[r] + rs;
        }
        // P -> LDS (f16, swizzled)
#pragma unroll
        for (int t = 0; t < 4; ++t)
#pragma unroll
            for (int r = 0; r < 4; ++r) {
                const int i  = ws * 16 + g4 * 4 + r;
                const int j  = t * 16 + m16;
                const int pa = (i * 128 + j * 2) ^ ((i & 7) << 4);
                *reinterpret_cast<unsigned short*>(&p_lds[g][pa]) = f2h(s[t][r]);
            }
        if (m16 == 0) {
#pragma unroll
            for (int r = 0; r < 4; ++r) scale_lds[g][ws * 16 + g4 * 4 + r] = sc[r];
        }
        // P/scales/flags visible; keep staging vmcnt in flight
        asm volatile("s_waitcnt lgkmcnt(0)\n\ts_barrier" ::: "memory");

        const int do_resc = flags[g][step & 1];
        if (tid == 0) { flags[0][(step & 1) ^ 1] = 0; flags[1][(step & 1) ^ 1] = 0; }
        if (havenext) *reinterpret_cast<u32x4*>(&k_lds[g][kwaddr]) = kn;

        if (do_resc) {
#pragma unroll
            for (int is = 0; is < 4; ++is)
#pragma unroll
                for (int r = 0; r < 4; ++r) {
                    const float scv = scale_lds[g][is * 16 + g4 * 4 + r];
#pragma unroll
                    for (int cs = 0; cs < 4; ++cs) oacc[is][cs][r] *= scv;
                }
        }
        // ---- PV ----
        __builtin_amdgcn_s_setprio(1);
#pragma unroll
        for (int jh = 0; jh < 2; ++jh) {
            f16x8 vfr[4];
#pragma unroll
            for (int cs = 0; cs < 4; ++cs) {
                const int c  = ws * 64 + cs * 16 + m16;
                const int va = (c * 128 + jh * 64 + g4 * 16) ^ ((c & 7) << 4);
                vfr[cs] = *reinterpret_cast<const f16x8*>(&v_lds[g][cur][va]);
            }
#pragma unroll
            for (int is = 0; is < 4; ++is) {
                const int i  = is * 16 + m16;
                const int pa = (i * 128 + jh * 64 + g4 * 16) ^ ((i & 7) << 4);
                const f16x8 pf = *reinterpret_cast<const f16x8*>(&p_lds[g][pa]);
#pragma unroll
                for (int cs = 0; cs < 4; ++cs)
                    oacc[is][cs] = __builtin_amdgcn_mfma_f32_16x16x32_f16(
                        pf, vfr[cs], oacc[is][cs], 0, 0, 0);
            }
        }
        __builtin_amdgcn_s_setprio(0);

        __syncthreads();   // drains vmcnt: next V buffer ready; LDS reads done
        cur ^= 1;
    }

    // ---- epilogue: merge the two j-groups (exact flash combine) ----
    if (m16 == 0) {
#pragma unroll
        for (int r = 0; r < 4; ++r) {
            mfin[g][ws * 16 + g4 * 4 + r] = mrow[r];
            lfin[g][ws * 16 + g4 * 4 + r] = lrow[r];
        }
    }
    __syncthreads();

    float* ocomb = reinterpret_cast<float*>(&v_lds[0][0][0]);   // [64][257] f32
    if (g == 0) {
#pragma unroll
        for (int is = 0; is < 4; ++is)
#pragma unroll
            for (int r = 0; r < 4; ++r) {
                const int i = is * 16 + g4 * 4 + r;
                const float ms = fmaxf(mfin[0][i], mfin[1][i]);
                const float fa = fexp2(mfin[0][i] - ms);
#pragma unroll
                for (int cs = 0; cs < 4; ++cs)
                    ocomb[i * 257 + ws * 64 + cs * 16 + m16] = oacc[is][cs][r] * fa;
            }
    }
    __syncthreads();
    if (g == 1) {
        const float gm = gamma[0];
#pragma unroll
        for (int is = 0; is < 4; ++is)
#pragma unroll
            for (int r = 0; r < 4; ++r) {
                const int i  = is * 16 + g4 * 4 + r;
                const float ma = mfin[0][i], mb2 = mfin[1][i];
                const float ms = fmaxf(ma, mb2);
                const float fa = fexp2(ma - ms), fb = fexp2(mb2 - ms);
                const float den  = lfin[0][i] * fa + lfin[1][i] * fb;
                const float rinv = 1.0f / den;
#pragma unroll
                for (int cs = 0; cs < 4; ++cs) {
                    const int c = ws * 64 + cs * 16 + m16;
                    const float val = ocomb[i * 257 + c] + oacc[is][cs][r] * fb;
                    const size_t idx = ((size_t)(b * CD + c)) * ND + i0 + i;
                    out[idx] = gm * (val * rinv) + x[idx];
                }
            }
    }
}

extern "C" void kernel_launch(void* const* d_in, const int* in_sizes, int n_in,
                              void* d_out, int out_size, void* d_ws, size_t ws_size,
                              hipStream_t stream) {
    const float* x     = (const float*)d_in[0];
    const float* wq    = (const float*)d_in[1];
    const float* bq    = (const float*)d_in[2];
    const float* wk    = (const float*)d_in[3];
    const float* bk    = (const float*)d_in[4];
    const float* wv    = (const float*)d_in[5];
    const float* bv    = (const float*)d_in[6];
    const float* gamma = (const float*)d_in[7];

    unsigned short* Qt = (unsigned short*)d_ws;               // 1MB (scaled by log2e)
    unsigned short* Kt = Qt + (size_t)NB * ND * CQ;           // 1MB
    unsigned short* V  = Kt + (size_t)NB * ND * CQ;           // 8MB
    unsigned short* Wh = V + (size_t)NB * CD * ND;            // 160KB
    unsigned short* xh = Wh + (size_t)320 * CD;               // 8MB
    float* out = (float*)d_out;

    wcvt_kernel<<<dim3(80),      dim3(256), 0, stream>>>(wq, wk, wv, Wh);
    xcvt_kernel<<<dim3(1024),    dim3(256), 0, stream>>>(x, xh);
    proj_kernel<<<dim3(NB * 64), dim3(320), 0, stream>>>(Wh, xh, bq, bk, bv, Qt, Kt, V);
    attn_kernel<<<dim3(NB * 64), dim3(512), 0, stream>>>(Qt, Kt, V, x, gamma, out);
}